// Round 1
// baseline (835.214 us; speedup 1.0000x reference)
//
#include <hip/hip_runtime.h>

#define EPS 1e-5f
#define CNTF 409600.0f   // N*T*V = 128*128*25

__device__ __forceinline__ float wave_sum(float v) {
#pragma unroll
    for (int off = 32; off > 0; off >>= 1)
        v += __shfl_down(v, off, 64);
    return v;
}

// ---- K1: conv_down (1x1, 64->16) + bias, writes xd_pre, accumulates BN stats
// grid 800, block 256; 2 positions per thread (800*256*2 = 409600)
__global__ __launch_bounds__(256) void k_down(
    const float* __restrict__ x, const float* __restrict__ Wd,
    const float* __restrict__ bd, float* __restrict__ xdp, float* __restrict__ st)
{
    __shared__ float Wt[1024];   // transposed: [c][o]
    __shared__ float bs[16];
    __shared__ float bins[32];
    const int tid = threadIdx.x;
    for (int i = tid; i < 1024; i += 256) Wt[i] = Wd[(i & 15) * 64 + (i >> 4)];
    if (tid < 16) bs[tid] = bd[tid];
    if (tid < 32) bins[tid] = 0.f;
    __syncthreads();

    float acc[2][16];
    int xb[2], wb[2];
#pragma unroll
    for (int j = 0; j < 2; j++) {
        int f = blockIdx.x * 512 + j * 256 + tid;   // flat (n, p) index
        int n = f / 3200, p = f - n * 3200;
        xb[j] = n * 204800 + p;
        wb[j] = n * 51200 + p;
#pragma unroll
        for (int o = 0; o < 16; o++) acc[j][o] = bs[o];
    }
    for (int c = 0; c < 64; c++) {
        float xv0 = x[xb[0] + c * 3200];
        float xv1 = x[xb[1] + c * 3200];
#pragma unroll
        for (int o = 0; o < 16; o++) {
            float wv = Wt[c * 16 + o];
            acc[0][o] += wv * xv0;
            acc[1][o] += wv * xv1;
        }
    }
#pragma unroll
    for (int j = 0; j < 2; j++)
#pragma unroll
        for (int o = 0; o < 16; o++) xdp[wb[j] + o * 3200] = acc[j][o];

    const int lane = tid & 63;
#pragma unroll
    for (int o = 0; o < 16; o++) {
        float sv = wave_sum(acc[0][o] + acc[1][o]);
        float qv = wave_sum(acc[0][o] * acc[0][o] + acc[1][o] * acc[1][o]);
        if (lane == 0) { atomicAdd(&bins[o], sv); atomicAdd(&bins[16 + o], qv); }
    }
    __syncthreads();
    if (tid < 32) atomicAdd(&st[tid], bins[tid]);
}

// ---- K3: recompute z2 and accumulate per-(s,o) BN stats.
// grid 1024, block 320; 4 (n,t) pairs per iter, 4 iters => 16 pairs/block
__global__ __launch_bounds__(320) void k_substats(
    const float* __restrict__ xdp, const float* __restrict__ PA,
    const float* __restrict__ Wsub, const float* __restrict__ bsub,
    const float* __restrict__ gd, const float* __restrict__ betad,
    const float* __restrict__ std_, float* __restrict__ stsub)
{
    __shared__ float PAs[3125];     // [s][v][u]
    __shared__ float Wss[1280];     // [s][o][c]
    __shared__ float bss[80];
    __shared__ float ad[16], cd[16];
    __shared__ float xds[4][400];   // [pair][c*25+u]
    __shared__ float bins[160];
    const int tid = threadIdx.x;
    for (int i = tid; i < 3125; i += 320) PAs[i] = PA[i];
    for (int i = tid; i < 1280; i += 320) Wss[i] = Wsub[i];
    if (tid < 80) bss[tid] = bsub[tid];
    if (tid < 160) bins[tid] = 0.f;
    if (tid < 16) {
        float m = std_[tid] * (1.f / CNTF);
        float var = std_[16 + tid] * (1.f / CNTF) - m * m;
        float a = gd[tid] * rsqrtf(var + EPS);
        ad[tid] = a; cd[tid] = betad[tid] - m * a;
    }

    const int pp = tid / 80, ch = tid - (tid / 80) * 80;
    const int s = ch / 16, o = ch - (ch / 16) * 16;
    float sacc = 0.f, qacc = 0.f;

    for (int it = 0; it < 4; it++) {
        __syncthreads();   // protects xds from previous iteration + makes ad/cd visible
        const int base = blockIdx.x * 16 + it * 4;
        for (int j = tid; j < 1600; j += 320) {
            int lp = j / 400, r = j - lp * 400;
            int c = r / 25;
            int nt = base + lp;
            int n = nt >> 7, t = nt & 127;
            float xv = xdp[n * 51200 + c * 3200 + t * 25 + (r - c * 25)];
            xds[lp][r] = fmaxf(ad[c] * xv + cd[c], 0.f);
        }
        __syncthreads();

        float e[25];
#pragma unroll
        for (int u = 0; u < 25; u++) e[u] = 0.f;
        for (int c = 0; c < 16; c++) {
            float wv = Wss[(s * 16 + o) * 16 + c];
#pragma unroll
            for (int u = 0; u < 25; u++) e[u] += wv * xds[pp][c * 25 + u];
        }
        for (int v = 0; v < 25; v++) {
            float z = bss[ch];
#pragma unroll
            for (int u = 0; u < 25; u++) z += e[u] * PAs[(s * 25 + v) * 25 + u];
            sacc += z; qacc += z * z;
        }
    }
    atomicAdd(&bins[ch], sacc);
    atomicAdd(&bins[80 + ch], qacc);
    __syncthreads();
    if (tid < 160) atomicAdd(&stsub[tid], bins[tid]);
}

// ---- K5: recompute z2, apply both BN affines, subset-0 broadcast add,
// write/accumulate acc (lives in d_out). thread <-> (pair, v); 10 pairs/block
template <int FIRST>
__global__ __launch_bounds__(256) void k_out(
    const float* __restrict__ xdp, const float* __restrict__ PA,
    const float* __restrict__ Wsub, const float* __restrict__ bsub,
    const float* __restrict__ gd, const float* __restrict__ betad,
    const float* __restrict__ gs, const float* __restrict__ betas,
    const float* __restrict__ std_, const float* __restrict__ stsub,
    float* __restrict__ out)
{
    __shared__ float PAs[3125];
    __shared__ float Wss[1280];
    __shared__ float asub[80], csub[80];
    __shared__ float ad[16], cd[16];
    __shared__ float xds[10][400];
    const int tid = threadIdx.x;
    for (int i = tid; i < 3125; i += 256) PAs[i] = PA[i];
    for (int i = tid; i < 1280; i += 256) Wss[i] = Wsub[i];
    if (tid < 16) {
        float m = std_[tid] * (1.f / CNTF);
        float var = std_[16 + tid] * (1.f / CNTF) - m * m;
        float a = gd[tid] * rsqrtf(var + EPS);
        ad[tid] = a; cd[tid] = betad[tid] - m * a;
    }
    if (tid < 80) {
        float m = stsub[tid] * (1.f / CNTF);
        float var = stsub[80 + tid] * (1.f / CNTF) - m * m;
        float a = gs[tid] * rsqrtf(var + EPS);
        asub[tid] = a;
        // z2 = zraw + b_sub; fold bias into the affine intercept
        csub[tid] = betas[tid] - m * a + a * bsub[tid];
    }
    __syncthreads();   // ad/cd ready before xds staging

    const int base = blockIdx.x * 10;
    for (int j = tid; j < 4000; j += 256) {
        int lp = j / 400, r = j - lp * 400;
        int c = r / 25;
        int nt = base + lp;
        if (nt < 16384) {
            int n = nt >> 7, t = nt & 127;
            float xv = xdp[n * 51200 + c * 3200 + t * 25 + (r - c * 25)];
            xds[lp][r] = fmaxf(ad[c] * xv + cd[c], 0.f);
        }
    }
    __syncthreads();

    if (tid >= 250) return;
    const int pp = tid / 25, v = tid - (tid / 25) * 25;
    const int nt = base + pp;
    if (nt >= 16384) return;
    const int n = nt >> 7, t = nt & 127;

    float w[5][16];
#pragma unroll
    for (int s = 0; s < 5; s++)
#pragma unroll
        for (int c = 0; c < 16; c++) w[s][c] = 0.f;

    for (int u = 0; u < 25; u++) {         // outer product: 21 LDS reads -> 80 FMA
        float pav[5];
#pragma unroll
        for (int s = 0; s < 5; s++) pav[s] = PAs[s * 625 + v * 25 + u];
#pragma unroll
        for (int c = 0; c < 16; c++) {
            float xc = xds[pp][c * 25 + u];
#pragma unroll
            for (int s = 0; s < 5; s++) w[s][c] += pav[s] * xc;
        }
    }

    float z0[16];
    const int obase = n * 204800 + t * 25 + v;
#pragma unroll
    for (int s = 0; s < 5; s++) {
#pragma unroll
        for (int o = 0; o < 16; o++) {
            float z = 0.f;
#pragma unroll
            for (int c = 0; c < 16; c++) z += Wss[(s * 16 + o) * 16 + c] * w[s][c];
            float zb = asub[s * 16 + o] * z + csub[s * 16 + o];
            if (s == 0) z0[o] = zb;
            else {
                int adr = obase + ((s - 1) * 16 + o) * 3200;
                float val = zb + z0[o];
                if (FIRST) out[adr] = val;
                else out[adr] += val;
            }
        }
    }
}

// ---- K6: per-(n,k)-row sum/sumsq of acc (in d_out)
__global__ __launch_bounds__(256) void k_accstats(const float* __restrict__ acc,
                                                  float* __restrict__ stout)
{
    __shared__ float bins[2];
    const int nk = blockIdx.x;          // 0..8191
    const int k = nk & 63;
    const float4* row = (const float4*)(acc + (size_t)nk * 3200);
    float s = 0.f, q = 0.f;
    for (int j = threadIdx.x; j < 800; j += 256) {
        float4 v = row[j];
        s += v.x + v.y + v.z + v.w;
        q += v.x * v.x + v.y * v.y + v.z * v.z + v.w * v.w;
    }
    if (threadIdx.x == 0) { bins[0] = 0.f; bins[1] = 0.f; }
    __syncthreads();
    s = wave_sum(s); q = wave_sum(q);
    if ((threadIdx.x & 63) == 0) { atomicAdd(&bins[0], s); atomicAdd(&bins[1], q); }
    __syncthreads();
    if (threadIdx.x == 0) {
        atomicAdd(&stout[k], bins[0]);
        atomicAdd(&stout[64 + k], bins[1]);
    }
}

// ---- K8: out = relu(bn(acc) + x), in place on d_out, float4
__global__ __launch_bounds__(256) void k_final(
    const float* __restrict__ x, const float* __restrict__ go,
    const float* __restrict__ bo, const float* __restrict__ stout,
    float* __restrict__ out)
{
    __shared__ float ao[64], co[64];
    const int tid = threadIdx.x;
    if (tid < 64) {
        float m = stout[tid] * (1.f / CNTF);
        float var = stout[64 + tid] * (1.f / CNTF) - m * m;
        float a = go[tid] * rsqrtf(var + EPS);
        ao[tid] = a; co[tid] = bo[tid] - m * a;
    }
    __syncthreads();
    const float4* x4 = (const float4*)x;
    float4* o4 = (float4*)out;
    for (int i = blockIdx.x * 256 + tid; i < 6553600; i += gridDim.x * 256) {
        int k = (i / 800) & 63;         // 3200/4 = 800 float4 per (n,k) row
        float a = ao[k], c = co[k];
        float4 vo = o4[i], vx = x4[i];
        vo.x = fmaxf(fmaf(a, vo.x, c) + vx.x, 0.f);
        vo.y = fmaxf(fmaf(a, vo.y, c) + vx.y, 0.f);
        vo.z = fmaxf(fmaf(a, vo.z, c) + vx.z, 0.f);
        vo.w = fmaxf(fmaf(a, vo.w, c) + vx.w, 0.f);
        o4[i] = vo;
    }
}

extern "C" void kernel_launch(void* const* d_in, const int* in_sizes, int n_in,
                              void* d_out, int out_size, void* d_ws, size_t ws_size,
                              hipStream_t stream)
{
    const float* x     = (const float*)d_in[0];
    const float* PA    = (const float*)d_in[1];   // (3,5,25,25)
    const float* Wd    = (const float*)d_in[2];   // (3,16,64)
    const float* bd    = (const float*)d_in[3];   // (3,16)
    const float* gd    = (const float*)d_in[4];
    const float* betad = (const float*)d_in[5];
    const float* Wsub  = (const float*)d_in[6];   // (3,5,16,16)
    const float* bsub  = (const float*)d_in[7];   // (3,5,16)
    const float* gsub  = (const float*)d_in[8];
    const float* betas = (const float*)d_in[9];
    const float* gout  = (const float*)d_in[10];  // (64,)
    const float* betao = (const float*)d_in[11];
    float* out = (float*)d_out;

    float* xdp   = (float*)d_ws;          // 6,553,600 floats (26.2 MB)
    float* stats = xdp + 6553600;         // 704 floats: [3][32] down, [3][160] sub, [128] out

    hipMemsetAsync(stats, 0, 704 * sizeof(float), stream);

    for (int l = 0; l < 3; l++) {
        float* st_d = stats + l * 32;
        float* st_s = stats + 96 + l * 160;
        k_down<<<800, 256, 0, stream>>>(x, Wd + l * 1024, bd + l * 16, xdp, st_d);
        k_substats<<<1024, 320, 0, stream>>>(xdp, PA + l * 3125, Wsub + l * 1280,
                                             bsub + l * 80, gd + l * 16, betad + l * 16,
                                             st_d, st_s);
        if (l == 0)
            k_out<1><<<1639, 256, 0, stream>>>(xdp, PA + l * 3125, Wsub + l * 1280,
                bsub + l * 80, gd + l * 16, betad + l * 16, gsub + l * 80,
                betas + l * 80, st_d, st_s, out);
        else
            k_out<0><<<1639, 256, 0, stream>>>(xdp, PA + l * 3125, Wsub + l * 1280,
                bsub + l * 80, gd + l * 16, betad + l * 16, gsub + l * 80,
                betas + l * 80, st_d, st_s, out);
    }
    k_accstats<<<8192, 256, 0, stream>>>(out, stats + 576);
    k_final<<<2048, 256, 0, stream>>>(x, gout, betao, stats + 576, out);
}